// Round 3
// baseline (1327.379 us; speedup 1.0000x reference)
//
#include <hip/hip_runtime.h>
#include <stdint.h>

#define N_P 100000
#define N_D 50000
#define NE  600000
#define F   128
#define FP  136   // padded LDS/global row stride (272B = 17*16B: 16B-aligned, 2-way-free banks)

#define DPARTS 64
#define PART_P ((N_P + DPARTS - 1) / DPARTS)   // 1563
#define PART_D ((N_D + DPARTS - 1) / DPARTS)   // 782

typedef __attribute__((ext_vector_type(8))) __bf16 bf16x8;
typedef __attribute__((ext_vector_type(4))) float  f32x4;

static __device__ __forceinline__ float bf2f(uint16_t u){
  union{float f;uint32_t i;} v; v.i = ((uint32_t)u)<<16; return v.f;
}
static __device__ __forceinline__ uint16_t f2bf(float f){
  union{float f;uint32_t i;} v; v.f = f;
  uint32_t i = v.i;
  uint32_t r = i + 0x7fffu + ((i>>16)&1u);   // round-to-nearest-even
  return (uint16_t)(r>>16);
}

// ---------------- degree counting: LDS-privatized, zero global atomics ------
// grid = 4*DPARTS blocks. Block (arr, part): scans the full index array,
// counts hits in its owned range in LDS, stores the range with plain stores.
__global__ __launch_bounds__(256) void k_deg(
    const int* __restrict__ pd_src, const int* __restrict__ pd_dst,
    const int* __restrict__ dp_src, const int* __restrict__ dp_dst,
    int* __restrict__ cnt_p_out, int* __restrict__ cnt_d_in,
    int* __restrict__ cnt_d_out, int* __restrict__ cnt_p_in){
  __shared__ int cnt[PART_P];
  const int arr = blockIdx.x >> 6, part = blockIdx.x & 63, tid = threadIdx.x;
  const int* src; int* dst; int N;
  switch(arr){
    case 0:  src = pd_src; dst = cnt_p_out; N = N_P; break;
    case 1:  src = pd_dst; dst = cnt_d_in;  N = N_D; break;
    case 2:  src = dp_src; dst = cnt_d_out; N = N_D; break;
    default: src = dp_dst; dst = cnt_p_in;  N = N_P; break;
  }
  const int PART = (N == N_P) ? PART_P : PART_D;
  const int lo = part * PART;
  const int nloc = min(lo + PART, N) - lo;
  for (int i = tid; i < PART_P; i += 256) cnt[i] = 0;
  __syncthreads();
  const uint4* s4 = (const uint4*)src;
  for (int i = tid; i < NE/4; i += 256){
    uint4 v = s4[i];
    int a0 = (int)v.x - lo, a1 = (int)v.y - lo, a2 = (int)v.z - lo, a3 = (int)v.w - lo;
    if ((unsigned)a0 < (unsigned)nloc) atomicAdd(&cnt[a0], 1);
    if ((unsigned)a1 < (unsigned)nloc) atomicAdd(&cnt[a1], 1);
    if ((unsigned)a2 < (unsigned)nloc) atomicAdd(&cnt[a2], 1);
    if ((unsigned)a3 < (unsigned)nloc) atomicAdd(&cnt[a3], 1);
  }
  __syncthreads();
  for (int i = tid; i < nloc; i += 256) dst[lo + i] = cnt[i];
}

__global__ void k_rs_all(const int* c_po, const int* c_pi, const int* c_do, const int* c_di,
                         float* r_po, float* r_pi, float* r_do, float* r_di){
  int i = blockIdx.x*256 + threadIdx.x;
  if (i < N_P){ r_po[i] = rsqrtf((float)max(c_po[i],1)); r_pi[i] = rsqrtf((float)max(c_pi[i],1)); }
  if (i < N_D){ r_do[i] = rsqrtf((float)max(c_do[i],1)); r_di[i] = rsqrtf((float)max(c_di[i],1)); }
}

// ---------------- hierarchical exclusive scan (two arrays in one pass set) ---
__global__ void k_scan1(const int* __restrict__ cA, int nA,
                        const int* __restrict__ cB, int nB,
                        int* __restrict__ bsums, int nbA){
  __shared__ int red[8];
  int b = blockIdx.x, t = threadIdx.x;
  const int* in; int n, bi, slot;
  if (b < nbA){ in = cA; n = nA; bi = b;       slot = bi; }
  else        { in = cB; n = nB; bi = b - nbA; slot = 256 + bi; }
  int i = bi*512 + t;
  int v = (i < n) ? in[i] : 0;
  #pragma unroll
  for (int o = 32; o; o >>= 1) v += __shfl_down(v, o, 64);
  if ((t & 63) == 0) red[t >> 6] = v;
  __syncthreads();
  if (t == 0){ int s = 0; for (int k = 0; k < 8; ++k) s += red[k]; bsums[slot] = s; }
}

__global__ void k_scan2(int* bsums, int nbA, int nbB){
  __shared__ int sh[256];
  int seg = blockIdx.x, t = threadIdx.x;
  int nb = seg ? nbB : nbA;
  int* p = bsums + seg*256;
  int v = (t < nb) ? p[t] : 0;
  sh[t] = v; __syncthreads();
  for (int ofs = 1; ofs < 256; ofs <<= 1){
    int u = (t >= ofs) ? sh[t-ofs] : 0; __syncthreads();
    sh[t] += u; __syncthreads();
  }
  if (t < nb) p[t] = sh[t] - v;   // exclusive
}

__global__ void k_scan3(const int* __restrict__ cA, int nA,
                        const int* __restrict__ cB, int nB,
                        const int* __restrict__ bsums, int nbA,
                        int* __restrict__ offA, int* __restrict__ offB){
  __shared__ int sh[512];
  int b = blockIdx.x, t = threadIdx.x;
  const int* in; int n, bi; int* out; int base;
  if (b < nbA){ in = cA; n = nA; bi = b;       out = offA; base = bsums[bi]; }
  else        { in = cB; n = nB; bi = b - nbA; out = offB; base = bsums[256+bi]; }
  int i = bi*512 + t;
  int v = (i < n) ? in[i] : 0;
  sh[t] = v; __syncthreads();
  for (int ofs = 1; ofs < 512; ofs <<= 1){
    int u = (t >= ofs) ? sh[t-ofs] : 0; __syncthreads();
    sh[t] += u; __syncthreads();
  }
  if (i < n) out[i] = base + sh[t] - v;
  if (b == 0 && t == 0){ offA[nA] = NE; offB[nB] = NE; }
}

// ---------------- CSR fill: LDS-ranked, zero global atomics -----------------
// grid = 2*DPARTS blocks. Block (graph, part): scans the full dst stream,
// loads matching src uint4 only on hit, ranks via LDS fill counters, writes
// col with plain stores into its owned contiguous range.
__global__ __launch_bounds__(256) void k_fill(
    const int* __restrict__ pd_src, const int* __restrict__ pd_dst,
    const int* __restrict__ dp_src, const int* __restrict__ dp_dst,
    const int* __restrict__ off_pd, int* __restrict__ col_pd,
    const int* __restrict__ off_dp, int* __restrict__ col_dp){
  __shared__ int offl[PART_P];
  __shared__ int fill[PART_P];
  const int gph = blockIdx.x >> 6, part = blockIdx.x & 63, tid = threadIdx.x;
  const int* dsts; const int* srcs; const int* off; int* col; int N;
  if (gph == 0){ dsts = pd_dst; srcs = pd_src; off = off_pd; col = col_pd; N = N_D; }
  else         { dsts = dp_dst; srcs = dp_src; off = off_dp; col = col_dp; N = N_P; }
  const int PART = (N == N_P) ? PART_P : PART_D;
  const int lo = part * PART;
  const int nloc = min(lo + PART, N) - lo;
  for (int i = tid; i < nloc; i += 256) offl[i] = off[lo + i];
  for (int i = tid; i < PART_P; i += 256) fill[i] = 0;
  __syncthreads();
  const uint4* d4 = (const uint4*)dsts;
  const uint4* s4 = (const uint4*)srcs;
  for (int i = tid; i < NE/4; i += 256){
    uint4 d = d4[i];
    int a0 = (int)d.x - lo, a1 = (int)d.y - lo, a2 = (int)d.z - lo, a3 = (int)d.w - lo;
    bool h0 = (unsigned)a0 < (unsigned)nloc, h1 = (unsigned)a1 < (unsigned)nloc;
    bool h2 = (unsigned)a2 < (unsigned)nloc, h3 = (unsigned)a3 < (unsigned)nloc;
    if (h0 | h1 | h2 | h3){
      uint4 s = s4[i];
      if (h0){ int r = atomicAdd(&fill[a0], 1); col[offl[a0] + r] = (int)s.x; }
      if (h1){ int r = atomicAdd(&fill[a1], 1); col[offl[a1] + r] = (int)s.y; }
      if (h2){ int r = atomicAdd(&fill[a2], 1); col[offl[a2] + r] = (int)s.z; }
      if (h3){ int r = atomicAdd(&fill[a3], 1); col[offl[a3] + r] = (int)s.w; }
    }
  }
}

// ---------------- fp32 -> prescaled bf16 feature conversion ----------------
__global__ void k_convert(const float4* __restrict__ hp, const float4* __restrict__ hd,
                          const float* __restrict__ rs_po, const float* __restrict__ rs_do,
                          uint2* __restrict__ P0, uint2* __restrict__ D0){
  int i = blockIdx.x*256 + threadIdx.x;
  const int nP4 = N_P*F/4, nD4 = N_D*F/4;
  if (i < nP4){
    float4 v = hp[i]; float s = rs_po[i >> 5];
    uint2 r;
    r.x = ((uint32_t)f2bf(v.y*s)<<16) | f2bf(v.x*s);
    r.y = ((uint32_t)f2bf(v.w*s)<<16) | f2bf(v.z*s);
    P0[i] = r;
  } else {
    int j = i - nP4;
    if (j < nD4){
      float4 v = hd[j]; float s = rs_do[j >> 5];
      uint2 r;
      r.x = ((uint32_t)f2bf(v.y*s)<<16) | f2bf(v.x*s);
      r.y = ((uint32_t)f2bf(v.w*s)<<16) | f2bf(v.z*s);
      D0[j] = r;
    }
  }
}

// ---------------- W (fp32 KxN row-major) -> bf16 W^T padded [N][FP] ----------
__global__ void k_prepw(const float* w0,const float* w1,const float* w2,
                        const float* w3,const float* w4,const float* w5,
                        uint16_t* __restrict__ wt){
  int m = blockIdx.x;
  const float* W;
  switch(m){ case 0:W=w0;break; case 1:W=w1;break; case 2:W=w2;break;
             case 3:W=w3;break; case 4:W=w4;break; default:W=w5; }
  uint16_t* T = wt + m*F*FP;
  for (int idx = threadIdx.x; idx < F*F; idx += 256){
    int k = idx >> 7, j = idx & 127;
    T[j*FP + k] = f2bf(W[idx]);
  }
}

// ---------------- fused gconv PAIR: two independent gconvs in one dispatch --
// blocks [0, nblkA): side A; blocks [nblkA, ...): side B.
// Aggregation: wave = 4 groups of 16 lanes; group g owns a row, lane l holds
// features [8l, 8l+8) (one dwordx4 per edge).
// OUT_MODE 0: bf16 intermediate pre-scaled by rs_next; 1: fp32 final.
template<int OUT_MODE>
__global__ __launch_bounds__(256, 3) void k_gconv2(
    const uint16_t* __restrict__ xA, const int* __restrict__ offAp, const int* __restrict__ colA,
    const float* __restrict__ rsA, const uint16_t* __restrict__ WtA, const float* __restrict__ biasA,
    const float* __restrict__ rsnA, void* __restrict__ outA, int ndA, int nblkA,
    const uint16_t* __restrict__ xB, const int* __restrict__ offBp, const int* __restrict__ colB,
    const float* __restrict__ rsB, const uint16_t* __restrict__ WtB, const float* __restrict__ biasB,
    const float* __restrict__ rsnB, void* __restrict__ outB, int ndB)
{
  __shared__ uint16_t wt_lds[F*FP];    // 34816 B
  __shared__ uint16_t m_lds[64*FP];    // 17408 B
  __shared__ float    b_lds[F];
  const int tid  = threadIdx.x;
  const int lane = tid & 63;
  const int wv   = tid >> 6;

  const uint16_t* x; const int* off; const int* col; const float* rs_in;
  const uint16_t* Wt; const float* bias; const float* rs_next; void* outp;
  int n_dst, bid;
  if ((int)blockIdx.x < nblkA){
    x = xA; off = offAp; col = colA; rs_in = rsA; Wt = WtA; bias = biasA;
    rs_next = rsnA; outp = outA; n_dst = ndA; bid = blockIdx.x;
  } else {
    x = xB; off = offBp; col = colB; rs_in = rsB; Wt = WtB; bias = biasB;
    rs_next = rsnB; outp = outB; n_dst = ndB; bid = blockIdx.x - nblkA;
  }

  // stage W^T (bf16, already padded in global) into LDS, 16B chunks
  {
    const uint4* s4 = (const uint4*)Wt;
    uint4* d4 = (uint4*)wt_lds;
    #pragma unroll
    for (int it = 0; it < 9; ++it){
      int idx = it*256 + tid;
      if (idx < (F*FP*2)/16) d4[idx] = s4[idx];
    }
    if (tid < F) b_lds[tid] = bias[tid];
  }

  // ---- aggregation ----
  const int row0 = bid*64 + wv*16;
  const int g    = lane >> 4;     // group
  const int l    = lane & 15;     // lane in group; features [8l, 8l+8)
  #pragma unroll
  for (int i = 0; i < 4; ++i){
    int r = row0 + i*4 + g;
    bool rv = r < n_dst;
    int e0 = rv ? off[r]   : 0;
    int e1 = rv ? off[r+1] : 0;
    float a0=0.f,a1=0.f,a2=0.f,a3=0.f,a4=0.f,a5=0.f,a6=0.f,a7=0.f;
    for (int e = e0; e < e1; e += 4){
      #pragma unroll
      for (int q = 0; q < 4; ++q){
        int ee = e + q;
        bool vld = ee < e1;
        int c = col[vld ? ee : e0];       // 16 lanes same addr -> broadcast
        uint4 u = *(const uint4*)(x + (size_t)c*F + l*8);
        if (vld){
          a0 += bf2f((uint16_t)u.x); a1 += bf2f((uint16_t)(u.x>>16));
          a2 += bf2f((uint16_t)u.y); a3 += bf2f((uint16_t)(u.y>>16));
          a4 += bf2f((uint16_t)u.z); a5 += bf2f((uint16_t)(u.z>>16));
          a6 += bf2f((uint16_t)u.w); a7 += bf2f((uint16_t)(u.w>>16));
        }
      }
    }
    float rs = rv ? rs_in[r] : 0.f;
    uint4 pk;
    pk.x = ((uint32_t)f2bf(a1*rs)<<16) | f2bf(a0*rs);
    pk.y = ((uint32_t)f2bf(a3*rs)<<16) | f2bf(a2*rs);
    pk.z = ((uint32_t)f2bf(a5*rs)<<16) | f2bf(a4*rs);
    pk.w = ((uint32_t)f2bf(a7*rs)<<16) | f2bf(a6*rs);
    *(uint4*)&m_lds[(wv*16 + i*4 + g)*FP + l*8] = pk;
  }
  __syncthreads();   // covers wt_lds for all waves (m_lds is wave-private)

  // ---- GEMM: 16 rows x 128 cols per wave via mfma_f32_16x16x32_bf16 ----
  f32x4 acc[8];
  #pragma unroll
  for (int t = 0; t < 8; ++t) acc[t] = (f32x4){0.f,0.f,0.f,0.f};
  const int mrow = lane & 15;        // A row / B col within tile
  const int kgrp = lane >> 4;        // k-slice group of 8
  #pragma unroll
  for (int k0 = 0; k0 < F; k0 += 32){
    bf16x8 a = *(const bf16x8*)&m_lds[(wv*16 + mrow)*FP + k0 + kgrp*8];
    #pragma unroll
    for (int t = 0; t < 8; ++t){
      bf16x8 b = *(const bf16x8*)&wt_lds[(t*16 + mrow)*FP + k0 + kgrp*8];
      acc[t] = __builtin_amdgcn_mfma_f32_16x16x32_bf16(a, b, acc[t], 0, 0, 0);
    }
  }

  // ---- epilogue: + bias, relu, (scale for next layer), store ----
  #pragma unroll
  for (int reg = 0; reg < 4; ++reg){
    int rr = row0 + kgrp*4 + reg;    // D row = (lane>>4)*4 + reg  [m89]
    if (rr < n_dst){
      float rsn = (OUT_MODE == 0) ? rs_next[rr] : 0.f;
      #pragma unroll
      for (int t = 0; t < 8; ++t){
        int n = t*16 + mrow;         // D col = lane&15
        float v = acc[t][reg] + b_lds[n];
        v = fmaxf(v, 0.f);
        if (OUT_MODE == 0){
          ((uint16_t*)outp)[rr*F + n] = f2bf(v * rsn);
        } else {
          ((float*)outp)[rr*F + n] = v;
        }
      }
    }
  }
}

extern "C" void kernel_launch(void* const* d_in, const int* in_sizes, int n_in,
                              void* d_out, int out_size, void* d_ws, size_t ws_size,
                              hipStream_t stream) {
  const float* h_p   = (const float*)d_in[0];
  const float* h_d   = (const float*)d_in[1];
  const int* pd_src  = (const int*)d_in[2];
  const int* pd_dst  = (const int*)d_in[3];
  const int* dp_src  = (const int*)d_in[4];
  const int* dp_dst  = (const int*)d_in[5];
  const float* W1_pd = (const float*)d_in[6];   const float* b1_pd = (const float*)d_in[7];
  const float* W1_dp = (const float*)d_in[8];   const float* b1_dp = (const float*)d_in[9];
  const float* W2_pd = (const float*)d_in[10];  const float* b2_pd = (const float*)d_in[11];
  const float* W2_dp = (const float*)d_in[12];  const float* b2_dp = (const float*)d_in[13];
  const float* W3_pd = (const float*)d_in[14];  const float* b3_pd = (const float*)d_in[15];
  const float* W3_dp = (const float*)d_in[16];  const float* b3_dp = (const float*)d_in[17];

  char* w = (char*)d_ws;
  size_t o = 0;
  auto take = [&](size_t bytes)->char*{
    char* p = w + o; o += (bytes + 255) & ~(size_t)255; return p;
  };

  int* cnt_p_out = (int*)take(4*(size_t)N_P);
  int* cnt_p_in  = (int*)take(4*(size_t)N_P);
  int* cnt_d_out = (int*)take(4*(size_t)N_D);
  int* cnt_d_in  = (int*)take(4*(size_t)N_D);
  int* off_pd   = (int*)take(4*(size_t)(N_D+1));
  int* off_dp   = (int*)take(4*(size_t)(N_P+1));
  int* bsums    = (int*)take(4*512);
  int* col_pd   = (int*)take(4*(size_t)NE);
  int* col_dp   = (int*)take(4*(size_t)NE);
  float* rs_p_out = (float*)take(4*(size_t)N_P);
  float* rs_p_in  = (float*)take(4*(size_t)N_P);
  float* rs_d_out = (float*)take(4*(size_t)N_D);
  float* rs_d_in  = (float*)take(4*(size_t)N_D);
  uint16_t* wt  = (uint16_t*)take(2*(size_t)6*F*FP);
  uint16_t* P0  = (uint16_t*)take(2*(size_t)N_P*F);
  uint16_t* P1  = (uint16_t*)take(2*(size_t)N_P*F);
  uint16_t* P2  = (uint16_t*)take(2*(size_t)N_P*F);
  uint16_t* D0  = (uint16_t*)take(2*(size_t)N_D*F);
  uint16_t* D1  = (uint16_t*)take(2*(size_t)N_D*F);
  uint16_t* D2  = (uint16_t*)take(2*(size_t)N_D*F);

  k_deg<<<4*DPARTS, 256, 0, stream>>>(pd_src, pd_dst, dp_src, dp_dst,
                                      cnt_p_out, cnt_d_in, cnt_d_out, cnt_p_in);
  k_rs_all<<<(N_P+255)/256, 256, 0, stream>>>(cnt_p_out, cnt_p_in, cnt_d_out, cnt_d_in,
                                              rs_p_out, rs_p_in, rs_d_out, rs_d_in);
  const int nbA = (N_D + 511)/512;   // 98
  const int nbB = (N_P + 511)/512;   // 196
  k_scan1<<<nbA+nbB, 512, 0, stream>>>(cnt_d_in, N_D, cnt_p_in, N_P, bsums, nbA);
  k_scan2<<<2, 256, 0, stream>>>(bsums, nbA, nbB);
  k_scan3<<<nbA+nbB, 512, 0, stream>>>(cnt_d_in, N_D, cnt_p_in, N_P, bsums, nbA, off_pd, off_dp);
  k_fill<<<2*DPARTS, 256, 0, stream>>>(pd_src, pd_dst, dp_src, dp_dst,
                                       off_pd, col_pd, off_dp, col_dp);
  k_convert<<<((N_P+N_D)*F/4 + 255)/256, 256, 0, stream>>>(
      (const float4*)h_p, (const float4*)h_d, rs_p_out, rs_d_out, (uint2*)P0, (uint2*)D0);
  k_prepw<<<6, 256, 0, stream>>>(W1_pd, W1_dp, W2_pd, W2_dp, W3_pd, W3_dp, wt);

  const int gd = (N_D + 63)/64, gp = (N_P + 63)/64;
  // layer 1 (both directions fused in one dispatch)
  k_gconv2<0><<<gd+gp, 256, 0, stream>>>(
      P0, off_pd, col_pd, rs_d_in, wt + 0*F*FP, b1_pd, rs_d_out, D1, N_D, gd,
      D0, off_dp, col_dp, rs_p_in, wt + 1*F*FP, b1_dp, rs_p_out, P1, N_P);
  // layer 2
  k_gconv2<0><<<gd+gp, 256, 0, stream>>>(
      P1, off_pd, col_pd, rs_d_in, wt + 2*F*FP, b2_pd, rs_d_out, D2, N_D, gd,
      D1, off_dp, col_dp, rs_p_in, wt + 3*F*FP, b2_dp, rs_p_out, P2, N_P);
  // layer 3 (fp32 outputs: h_p3 first, then h_d3)
  k_gconv2<1><<<gd+gp, 256, 0, stream>>>(
      P2, off_pd, col_pd, rs_d_in, wt + 4*F*FP, b3_pd, nullptr, (float*)d_out + (size_t)N_P*F, N_D, gd,
      D2, off_dp, col_dp, rs_p_in, wt + 5*F*FP, b3_dp, nullptr, (float*)d_out, N_P);
}

// Round 4
// 683.549 us; speedup vs baseline: 1.9419x; 1.9419x over previous
//
#include <hip/hip_runtime.h>
#include <stdint.h>

#define N_P 100000
#define N_D 50000
#define NE  600000
#define F   128
#define FP  136   // padded LDS/global row stride (272B = 17*16B: 16B-aligned, 2-way-free banks)

// counting-sort build params
#define NCHK   32
#define CHKE   18752                 // edges per chunk (mult of 4); last chunk = 18688
#define HPARTS 16
#define HPART_P (N_P/HPARTS)         // 6250
#define HPART_D (N_D/HPARTS)         // 3125
// hist layout (ints): A0 pd_src[32][N_P] | A1 pd_dst[32][N_D] | A2 dp_src[32][N_D] | A3 dp_dst[32][N_P]
#define HOFS_A0 ((size_t)0)
#define HOFS_A1 ((size_t)32*N_P)
#define HOFS_A2 ((size_t)32*N_P + (size_t)32*N_D)
#define HOFS_A3 ((size_t)32*N_P + (size_t)64*N_D)

typedef __attribute__((ext_vector_type(8))) __bf16 bf16x8;
typedef __attribute__((ext_vector_type(4))) float  f32x4;

static __device__ __forceinline__ float bf2f(uint16_t u){
  union{float f;uint32_t i;} v; v.i = ((uint32_t)u)<<16; return v.f;
}
static __device__ __forceinline__ uint16_t f2bf(float f){
  union{float f;uint32_t i;} v; v.f = f;
  uint32_t i = v.i;
  uint32_t r = i + 0x7fffu + ((i>>16)&1u);   // round-to-nearest-even
  return (uint16_t)(r>>16);
}

// ---------------- phase 1: per-(array, part, chunk) LDS histogram -----------
// grid = 4*HPARTS*NCHK = 2048 blocks; zero global atomics, full-machine parallel.
__global__ __launch_bounds__(256) void k_hist(
    const int* __restrict__ pd_src, const int* __restrict__ pd_dst,
    const int* __restrict__ dp_src, const int* __restrict__ dp_dst,
    int* __restrict__ hist){
  __shared__ int cnt[HPART_P];
  const int b = blockIdx.x;
  const int arr = b >> 9, part = (b >> 5) & 15, chunk = b & 31;
  const int* src; int N; size_t hofs;
  switch(arr){
    case 0:  src = pd_src; N = N_P; hofs = HOFS_A0; break;
    case 1:  src = pd_dst; N = N_D; hofs = HOFS_A1; break;
    case 2:  src = dp_src; N = N_D; hofs = HOFS_A2; break;
    default: src = dp_dst; N = N_P; hofs = HOFS_A3; break;
  }
  const int PART = N / HPARTS;
  const int lo = part * PART;
  for (int i = threadIdx.x; i < PART; i += 256) cnt[i] = 0;
  __syncthreads();
  const int e0 = chunk*CHKE, e1 = min(e0 + CHKE, NE);
  const uint4* s4 = (const uint4*)(src + e0);
  const int n4 = (e1 - e0) >> 2;
  for (int i = threadIdx.x; i < n4; i += 256){
    uint4 v = s4[i];
    int a0 = (int)v.x - lo, a1 = (int)v.y - lo, a2 = (int)v.z - lo, a3 = (int)v.w - lo;
    if ((unsigned)a0 < (unsigned)PART) atomicAdd(&cnt[a0], 1);
    if ((unsigned)a1 < (unsigned)PART) atomicAdd(&cnt[a1], 1);
    if ((unsigned)a2 < (unsigned)PART) atomicAdd(&cnt[a2], 1);
    if ((unsigned)a3 < (unsigned)PART) atomicAdd(&cnt[a3], 1);
  }
  __syncthreads();
  int* out = hist + hofs + (size_t)chunk*N + lo;
  for (int i = threadIdx.x; i < PART; i += 256) out[i] = cnt[i];
}

// ---------------- phase 2: chunk-prefix (dst arrays) + degrees + rsqrt ------
// grid = dim3((N_P+255)/256, 4); arr = blockIdx.y.
__global__ void k_sumdeg(int* __restrict__ hist,
                         int* __restrict__ cnt_d_in, int* __restrict__ cnt_p_in,
                         float* __restrict__ rs_p_out, float* __restrict__ rs_p_in,
                         float* __restrict__ rs_d_out, float* __restrict__ rs_d_in){
  const int idx = blockIdx.x*256 + threadIdx.x;
  const int arr = blockIdx.y;
  int N; size_t hofs; bool pre;
  switch(arr){
    case 0:  N = N_P; hofs = HOFS_A0; pre = false; break;  // pd_src -> rs_p_out
    case 1:  N = N_D; hofs = HOFS_A1; pre = true;  break;  // pd_dst -> cnt_d_in, rs_d_in
    case 2:  N = N_D; hofs = HOFS_A2; pre = false; break;  // dp_src -> rs_d_out
    default: N = N_P; hofs = HOFS_A3; pre = true;  break;  // dp_dst -> cnt_p_in, rs_p_in
  }
  if (idx >= N) return;
  int* base = hist + hofs + idx;
  int run = 0;
  if (pre){
    #pragma unroll 4
    for (int c = 0; c < NCHK; ++c){
      int v = base[(size_t)c*N]; base[(size_t)c*N] = run; run += v;
    }
  } else {
    #pragma unroll 4
    for (int c = 0; c < NCHK; ++c) run += base[(size_t)c*N];
  }
  float rs = rsqrtf((float)max(run, 1));
  switch(arr){
    case 0:  rs_p_out[idx] = rs; break;
    case 1:  cnt_d_in[idx] = run; rs_d_in[idx] = rs; break;
    case 2:  rs_d_out[idx] = rs; break;
    default: cnt_p_in[idx] = run; rs_p_in[idx] = rs; break;
  }
}

// ---------------- hierarchical exclusive scan (two arrays in one pass set) ---
__global__ void k_scan1(const int* __restrict__ cA, int nA,
                        const int* __restrict__ cB, int nB,
                        int* __restrict__ bsums, int nbA){
  __shared__ int red[8];
  int b = blockIdx.x, t = threadIdx.x;
  const int* in; int n, bi, slot;
  if (b < nbA){ in = cA; n = nA; bi = b;       slot = bi; }
  else        { in = cB; n = nB; bi = b - nbA; slot = 256 + bi; }
  int i = bi*512 + t;
  int v = (i < n) ? in[i] : 0;
  #pragma unroll
  for (int o = 32; o; o >>= 1) v += __shfl_down(v, o, 64);
  if ((t & 63) == 0) red[t >> 6] = v;
  __syncthreads();
  if (t == 0){ int s = 0; for (int k = 0; k < 8; ++k) s += red[k]; bsums[slot] = s; }
}

__global__ void k_scan2(int* bsums, int nbA, int nbB){
  __shared__ int sh[256];
  int seg = blockIdx.x, t = threadIdx.x;
  int nb = seg ? nbB : nbA;
  int* p = bsums + seg*256;
  int v = (t < nb) ? p[t] : 0;
  sh[t] = v; __syncthreads();
  for (int ofs = 1; ofs < 256; ofs <<= 1){
    int u = (t >= ofs) ? sh[t-ofs] : 0; __syncthreads();
    sh[t] += u; __syncthreads();
  }
  if (t < nb) p[t] = sh[t] - v;   // exclusive
}

__global__ void k_scan3(const int* __restrict__ cA, int nA,
                        const int* __restrict__ cB, int nB,
                        const int* __restrict__ bsums, int nbA,
                        int* __restrict__ offA, int* __restrict__ offB){
  __shared__ int sh[512];
  int b = blockIdx.x, t = threadIdx.x;
  const int* in; int n, bi; int* out; int base;
  if (b < nbA){ in = cA; n = nA; bi = b;       out = offA; base = bsums[bi]; }
  else        { in = cB; n = nB; bi = b - nbA; out = offB; base = bsums[256+bi]; }
  int i = bi*512 + t;
  int v = (i < n) ? in[i] : 0;
  sh[t] = v; __syncthreads();
  for (int ofs = 1; ofs < 512; ofs <<= 1){
    int u = (t >= ofs) ? sh[t-ofs] : 0; __syncthreads();
    sh[t] += u; __syncthreads();
  }
  if (i < n) out[i] = base + sh[t] - v;
  if (b == 0 && t == 0){ offA[nA] = NE; offB[nB] = NE; }
}

// ---------------- phase 3: scatter (LDS-ranked, zero global atomics) --------
// grid = 2*HPARTS*NCHK = 1024 blocks. base = off + chunk-prefix; rank via LDS.
__global__ __launch_bounds__(256) void k_scatter(
    const int* __restrict__ pd_src, const int* __restrict__ pd_dst,
    const int* __restrict__ dp_src, const int* __restrict__ dp_dst,
    const int* __restrict__ off_pd, const int* __restrict__ off_dp,
    const int* __restrict__ hist,
    int* __restrict__ col_pd, int* __restrict__ col_dp){
  __shared__ int base[HPART_P];
  __shared__ int fill[HPART_P];
  const int b = blockIdx.x;
  const int gph = b >> 9, part = (b >> 5) & 15, chunk = b & 31;
  const int* dsts; const int* srcs; const int* off; int* col; int N; size_t hofs;
  if (gph == 0){ dsts = pd_dst; srcs = pd_src; off = off_pd; col = col_pd; N = N_D; hofs = HOFS_A1; }
  else         { dsts = dp_dst; srcs = dp_src; off = off_dp; col = col_dp; N = N_P; hofs = HOFS_A3; }
  const int PART = N / HPARTS;
  const int lo = part * PART;
  const int* hc   = hist + hofs + (size_t)chunk*N + lo;
  const int* offp = off + lo;
  for (int i = threadIdx.x; i < PART; i += 256){ base[i] = offp[i] + hc[i]; fill[i] = 0; }
  __syncthreads();
  const int e0 = chunk*CHKE, e1 = min(e0 + CHKE, NE);
  const uint4* d4 = (const uint4*)(dsts + e0);
  const int n4 = (e1 - e0) >> 2;
  for (int i = threadIdx.x; i < n4; i += 256){
    uint4 d = d4[i];
    int a0 = (int)d.x - lo, a1 = (int)d.y - lo, a2 = (int)d.z - lo, a3 = (int)d.w - lo;
    int e = e0 + 4*i;
    if ((unsigned)a0 < (unsigned)PART){ int r = atomicAdd(&fill[a0], 1); col[base[a0] + r] = srcs[e+0]; }
    if ((unsigned)a1 < (unsigned)PART){ int r = atomicAdd(&fill[a1], 1); col[base[a1] + r] = srcs[e+1]; }
    if ((unsigned)a2 < (unsigned)PART){ int r = atomicAdd(&fill[a2], 1); col[base[a2] + r] = srcs[e+2]; }
    if ((unsigned)a3 < (unsigned)PART){ int r = atomicAdd(&fill[a3], 1); col[base[a3] + r] = srcs[e+3]; }
  }
}

// ---------------- fp32 -> prescaled bf16 feature conversion ----------------
__global__ void k_convert(const float4* __restrict__ hp, const float4* __restrict__ hd,
                          const float* __restrict__ rs_po, const float* __restrict__ rs_do,
                          uint2* __restrict__ P0, uint2* __restrict__ D0){
  int i = blockIdx.x*256 + threadIdx.x;
  const int nP4 = N_P*F/4, nD4 = N_D*F/4;
  if (i < nP4){
    float4 v = hp[i]; float s = rs_po[i >> 5];
    uint2 r;
    r.x = ((uint32_t)f2bf(v.y*s)<<16) | f2bf(v.x*s);
    r.y = ((uint32_t)f2bf(v.w*s)<<16) | f2bf(v.z*s);
    P0[i] = r;
  } else {
    int j = i - nP4;
    if (j < nD4){
      float4 v = hd[j]; float s = rs_do[j >> 5];
      uint2 r;
      r.x = ((uint32_t)f2bf(v.y*s)<<16) | f2bf(v.x*s);
      r.y = ((uint32_t)f2bf(v.w*s)<<16) | f2bf(v.z*s);
      D0[j] = r;
    }
  }
}

// ---------------- W (fp32 KxN row-major) -> bf16 W^T padded [N][FP] ----------
__global__ void k_prepw(const float* w0,const float* w1,const float* w2,
                        const float* w3,const float* w4,const float* w5,
                        uint16_t* __restrict__ wt){
  int m = blockIdx.x;
  const float* W;
  switch(m){ case 0:W=w0;break; case 1:W=w1;break; case 2:W=w2;break;
             case 3:W=w3;break; case 4:W=w4;break; default:W=w5; }
  uint16_t* T = wt + m*F*FP;
  for (int idx = threadIdx.x; idx < F*F; idx += 256){
    int k = idx >> 7, j = idx & 127;
    T[j*FP + k] = f2bf(W[idx]);
  }
}

// ---------------- fused gconv PAIR: two independent gconvs in one dispatch --
// blocks [0, nblkA): side A; blocks [nblkA, ...): side B.
// Aggregation: wave = 4 groups of 16 lanes; group g owns a row, lane l holds
// features [8l, 8l+8) (one dwordx4 per edge).
// OUT_MODE 0: bf16 intermediate pre-scaled by rs_next; 1: fp32 final.
template<int OUT_MODE>
__global__ __launch_bounds__(256, 3) void k_gconv2(
    const uint16_t* __restrict__ xA, const int* __restrict__ offAp, const int* __restrict__ colA,
    const float* __restrict__ rsA, const uint16_t* __restrict__ WtA, const float* __restrict__ biasA,
    const float* __restrict__ rsnA, void* __restrict__ outA, int ndA, int nblkA,
    const uint16_t* __restrict__ xB, const int* __restrict__ offBp, const int* __restrict__ colB,
    const float* __restrict__ rsB, const uint16_t* __restrict__ WtB, const float* __restrict__ biasB,
    const float* __restrict__ rsnB, void* __restrict__ outB, int ndB)
{
  __shared__ uint16_t wt_lds[F*FP];    // 34816 B
  __shared__ uint16_t m_lds[64*FP];    // 17408 B
  __shared__ float    b_lds[F];
  const int tid  = threadIdx.x;
  const int lane = tid & 63;
  const int wv   = tid >> 6;

  const uint16_t* x; const int* off; const int* col; const float* rs_in;
  const uint16_t* Wt; const float* bias; const float* rs_next; void* outp;
  int n_dst, bid;
  if ((int)blockIdx.x < nblkA){
    x = xA; off = offAp; col = colA; rs_in = rsA; Wt = WtA; bias = biasA;
    rs_next = rsnA; outp = outA; n_dst = ndA; bid = blockIdx.x;
  } else {
    x = xB; off = offBp; col = colB; rs_in = rsB; Wt = WtB; bias = biasB;
    rs_next = rsnB; outp = outB; n_dst = ndB; bid = blockIdx.x - nblkA;
  }

  // stage W^T (bf16, already padded in global) into LDS, 16B chunks
  {
    const uint4* s4 = (const uint4*)Wt;
    uint4* d4 = (uint4*)wt_lds;
    #pragma unroll
    for (int it = 0; it < 9; ++it){
      int idx = it*256 + tid;
      if (idx < (F*FP*2)/16) d4[idx] = s4[idx];
    }
    if (tid < F) b_lds[tid] = bias[tid];
  }

  // ---- aggregation ----
  const int row0 = bid*64 + wv*16;
  const int g    = lane >> 4;     // group
  const int l    = lane & 15;     // lane in group; features [8l, 8l+8)
  #pragma unroll
  for (int i = 0; i < 4; ++i){
    int r = row0 + i*4 + g;
    bool rv = r < n_dst;
    int e0 = rv ? off[r]   : 0;
    int e1 = rv ? off[r+1] : 0;
    float a0=0.f,a1=0.f,a2=0.f,a3=0.f,a4=0.f,a5=0.f,a6=0.f,a7=0.f;
    for (int e = e0; e < e1; e += 4){
      #pragma unroll
      for (int q = 0; q < 4; ++q){
        int ee = e + q;
        bool vld = ee < e1;
        int c = col[vld ? ee : e0];       // 16 lanes same addr -> broadcast
        uint4 u = *(const uint4*)(x + (size_t)c*F + l*8);
        if (vld){
          a0 += bf2f((uint16_t)u.x); a1 += bf2f((uint16_t)(u.x>>16));
          a2 += bf2f((uint16_t)u.y); a3 += bf2f((uint16_t)(u.y>>16));
          a4 += bf2f((uint16_t)u.z); a5 += bf2f((uint16_t)(u.z>>16));
          a6 += bf2f((uint16_t)u.w); a7 += bf2f((uint16_t)(u.w>>16));
        }
      }
    }
    float rs = rv ? rs_in[r] : 0.f;
    uint4 pk;
    pk.x = ((uint32_t)f2bf(a1*rs)<<16) | f2bf(a0*rs);
    pk.y = ((uint32_t)f2bf(a3*rs)<<16) | f2bf(a2*rs);
    pk.z = ((uint32_t)f2bf(a5*rs)<<16) | f2bf(a4*rs);
    pk.w = ((uint32_t)f2bf(a7*rs)<<16) | f2bf(a6*rs);
    *(uint4*)&m_lds[(wv*16 + i*4 + g)*FP + l*8] = pk;
  }
  __syncthreads();   // covers wt_lds for all waves (m_lds is wave-private)

  // ---- GEMM: 16 rows x 128 cols per wave via mfma_f32_16x16x32_bf16 ----
  f32x4 acc[8];
  #pragma unroll
  for (int t = 0; t < 8; ++t) acc[t] = (f32x4){0.f,0.f,0.f,0.f};
  const int mrow = lane & 15;        // A row / B col within tile
  const int kgrp = lane >> 4;        // k-slice group of 8
  #pragma unroll
  for (int k0 = 0; k0 < F; k0 += 32){
    bf16x8 a = *(const bf16x8*)&m_lds[(wv*16 + mrow)*FP + k0 + kgrp*8];
    #pragma unroll
    for (int t = 0; t < 8; ++t){
      bf16x8 b = *(const bf16x8*)&wt_lds[(t*16 + mrow)*FP + k0 + kgrp*8];
      acc[t] = __builtin_amdgcn_mfma_f32_16x16x32_bf16(a, b, acc[t], 0, 0, 0);
    }
  }

  // ---- epilogue: + bias, relu, (scale for next layer), store ----
  #pragma unroll
  for (int reg = 0; reg < 4; ++reg){
    int rr = row0 + kgrp*4 + reg;    // D row = (lane>>4)*4 + reg  [m89]
    if (rr < n_dst){
      float rsn = (OUT_MODE == 0) ? rs_next[rr] : 0.f;
      #pragma unroll
      for (int t = 0; t < 8; ++t){
        int n = t*16 + mrow;         // D col = lane&15
        float v = acc[t][reg] + b_lds[n];
        v = fmaxf(v, 0.f);
        if (OUT_MODE == 0){
          ((uint16_t*)outp)[rr*F + n] = f2bf(v * rsn);
        } else {
          ((float*)outp)[rr*F + n] = v;
        }
      }
    }
  }
}

extern "C" void kernel_launch(void* const* d_in, const int* in_sizes, int n_in,
                              void* d_out, int out_size, void* d_ws, size_t ws_size,
                              hipStream_t stream) {
  const float* h_p   = (const float*)d_in[0];
  const float* h_d   = (const float*)d_in[1];
  const int* pd_src  = (const int*)d_in[2];
  const int* pd_dst  = (const int*)d_in[3];
  const int* dp_src  = (const int*)d_in[4];
  const int* dp_dst  = (const int*)d_in[5];
  const float* W1_pd = (const float*)d_in[6];   const float* b1_pd = (const float*)d_in[7];
  const float* W1_dp = (const float*)d_in[8];   const float* b1_dp = (const float*)d_in[9];
  const float* W2_pd = (const float*)d_in[10];  const float* b2_pd = (const float*)d_in[11];
  const float* W2_dp = (const float*)d_in[12];  const float* b2_dp = (const float*)d_in[13];
  const float* W3_pd = (const float*)d_in[14];  const float* b3_pd = (const float*)d_in[15];
  const float* W3_dp = (const float*)d_in[16];  const float* b3_dp = (const float*)d_in[17];

  char* w = (char*)d_ws;
  size_t o = 0;
  auto take = [&](size_t bytes)->char*{
    char* p = w + o; o += (bytes + 255) & ~(size_t)255; return p;
  };

  int* cnt_d_in  = (int*)take(4*(size_t)N_D);
  int* cnt_p_in  = (int*)take(4*(size_t)N_P);
  int* off_pd   = (int*)take(4*(size_t)(N_D+1));
  int* off_dp   = (int*)take(4*(size_t)(N_P+1));
  int* bsums    = (int*)take(4*512);
  int* col_pd   = (int*)take(4*(size_t)NE);
  int* col_dp   = (int*)take(4*(size_t)NE);
  float* rs_p_out = (float*)take(4*(size_t)N_P);
  float* rs_p_in  = (float*)take(4*(size_t)N_P);
  float* rs_d_out = (float*)take(4*(size_t)N_D);
  float* rs_d_in  = (float*)take(4*(size_t)N_D);
  uint16_t* wt  = (uint16_t*)take(2*(size_t)6*F*FP);
  uint16_t* P0  = (uint16_t*)take(2*(size_t)N_P*F);
  uint16_t* P1  = (uint16_t*)take(2*(size_t)N_P*F);
  uint16_t* P2  = (uint16_t*)take(2*(size_t)N_P*F);
  uint16_t* D0  = (uint16_t*)take(2*(size_t)N_D*F);
  uint16_t* D1  = (uint16_t*)take(2*(size_t)N_D*F);
  uint16_t* D2  = (uint16_t*)take(2*(size_t)N_D*F);

  // hist (38.4 MB) aliases P1+P2 (51.2 MB): dead until layer-1 gconv, which
  // runs strictly after k_scatter on the same stream.
  int* hist = (int*)P1;

  k_hist<<<4*HPARTS*NCHK, 256, 0, stream>>>(pd_src, pd_dst, dp_src, dp_dst, hist);
  k_sumdeg<<<dim3((N_P+255)/256, 4), 256, 0, stream>>>(
      hist, cnt_d_in, cnt_p_in, rs_p_out, rs_p_in, rs_d_out, rs_d_in);
  const int nbA = (N_D + 511)/512;   // 98
  const int nbB = (N_P + 511)/512;   // 196
  k_scan1<<<nbA+nbB, 512, 0, stream>>>(cnt_d_in, N_D, cnt_p_in, N_P, bsums, nbA);
  k_scan2<<<2, 256, 0, stream>>>(bsums, nbA, nbB);
  k_scan3<<<nbA+nbB, 512, 0, stream>>>(cnt_d_in, N_D, cnt_p_in, N_P, bsums, nbA, off_pd, off_dp);
  k_scatter<<<2*HPARTS*NCHK, 256, 0, stream>>>(pd_src, pd_dst, dp_src, dp_dst,
                                               off_pd, off_dp, hist, col_pd, col_dp);
  k_convert<<<((N_P+N_D)*F/4 + 255)/256, 256, 0, stream>>>(
      (const float4*)h_p, (const float4*)h_d, rs_p_out, rs_d_out, (uint2*)P0, (uint2*)D0);
  k_prepw<<<6, 256, 0, stream>>>(W1_pd, W1_dp, W2_pd, W2_dp, W3_pd, W3_dp, wt);

  const int gd = (N_D + 63)/64, gp = (N_P + 63)/64;
  // layer 1 (both directions fused in one dispatch)
  k_gconv2<0><<<gd+gp, 256, 0, stream>>>(
      P0, off_pd, col_pd, rs_d_in, wt + 0*F*FP, b1_pd, rs_d_out, D1, N_D, gd,
      D0, off_dp, col_dp, rs_p_in, wt + 1*F*FP, b1_dp, rs_p_out, P1, N_P);
  // layer 2
  k_gconv2<0><<<gd+gp, 256, 0, stream>>>(
      P1, off_pd, col_pd, rs_d_in, wt + 2*F*FP, b2_pd, rs_d_out, D2, N_D, gd,
      D1, off_dp, col_dp, rs_p_in, wt + 3*F*FP, b2_dp, rs_p_out, P2, N_P);
  // layer 3 (fp32 outputs: h_p3 first, then h_d3)
  k_gconv2<1><<<gd+gp, 256, 0, stream>>>(
      P2, off_pd, col_pd, rs_d_in, wt + 4*F*FP, b3_pd, nullptr, (float*)d_out + (size_t)N_P*F, N_D, gd,
      D2, off_dp, col_dp, rs_p_in, wt + 5*F*FP, b3_dp, nullptr, (float*)d_out, N_P);
}

// Round 5
// 533.512 us; speedup vs baseline: 2.4880x; 1.2812x over previous
//
#include <hip/hip_runtime.h>
#include <stdint.h>

#define N_P 100000
#define N_D 50000
#define NE  600000
#define F   128
#define FP  136   // padded LDS/global row stride (272B = 17*16B: 16B-aligned, 2-way-free banks)

// counting-sort build params
#define NCHK   32
#define CHKE   18752                 // edges per chunk (mult of 4); last chunk = 18688
#define HPARTS 16
#define HPART_P (N_P/HPARTS)         // 6250
#define HPART_D (N_D/HPARTS)         // 3125
// hist layout (ints): A0 pd_src[32][N_P] | A1 pd_dst[32][N_D] | A2 dp_src[32][N_D] | A3 dp_dst[32][N_P]
#define HOFS_A0 ((size_t)0)
#define HOFS_A1 ((size_t)32*N_P)
#define HOFS_A2 ((size_t)32*N_P + (size_t)32*N_D)
#define HOFS_A3 ((size_t)32*N_P + (size_t)64*N_D)

typedef __attribute__((ext_vector_type(8))) __bf16 bf16x8;
typedef __attribute__((ext_vector_type(4))) float  f32x4;

static __device__ __forceinline__ float bf2f(uint16_t u){
  union{float f;uint32_t i;} v; v.i = ((uint32_t)u)<<16; return v.f;
}
static __device__ __forceinline__ uint16_t f2bf(float f){
  union{float f;uint32_t i;} v; v.f = f;
  uint32_t i = v.i;
  uint32_t r = i + 0x7fffu + ((i>>16)&1u);   // round-to-nearest-even
  return (uint16_t)(r>>16);
}

// ---------------- phase 1: per-(array, part, chunk) LDS histogram -----------
__global__ __launch_bounds__(256) void k_hist(
    const int* __restrict__ pd_src, const int* __restrict__ pd_dst,
    const int* __restrict__ dp_src, const int* __restrict__ dp_dst,
    int* __restrict__ hist){
  __shared__ int cnt[HPART_P];
  const int b = blockIdx.x;
  const int arr = b >> 9, part = (b >> 5) & 15, chunk = b & 31;
  const int* src; int N; size_t hofs;
  switch(arr){
    case 0:  src = pd_src; N = N_P; hofs = HOFS_A0; break;
    case 1:  src = pd_dst; N = N_D; hofs = HOFS_A1; break;
    case 2:  src = dp_src; N = N_D; hofs = HOFS_A2; break;
    default: src = dp_dst; N = N_P; hofs = HOFS_A3; break;
  }
  const int PART = N / HPARTS;
  const int lo = part * PART;
  for (int i = threadIdx.x; i < PART; i += 256) cnt[i] = 0;
  __syncthreads();
  const int e0 = chunk*CHKE, e1 = min(e0 + CHKE, NE);
  const uint4* s4 = (const uint4*)(src + e0);
  const int n4 = (e1 - e0) >> 2;
  for (int i = threadIdx.x; i < n4; i += 256){
    uint4 v = s4[i];
    int a0 = (int)v.x - lo, a1 = (int)v.y - lo, a2 = (int)v.z - lo, a3 = (int)v.w - lo;
    if ((unsigned)a0 < (unsigned)PART) atomicAdd(&cnt[a0], 1);
    if ((unsigned)a1 < (unsigned)PART) atomicAdd(&cnt[a1], 1);
    if ((unsigned)a2 < (unsigned)PART) atomicAdd(&cnt[a2], 1);
    if ((unsigned)a3 < (unsigned)PART) atomicAdd(&cnt[a3], 1);
  }
  __syncthreads();
  int* out = hist + hofs + (size_t)chunk*N + lo;
  for (int i = threadIdx.x; i < PART; i += 256) out[i] = cnt[i];
}

// ---------------- phase 2: chunk-prefix (dst arrays) + degrees + rsqrt ------
__global__ void k_sumdeg(int* __restrict__ hist,
                         int* __restrict__ cnt_d_in, int* __restrict__ cnt_p_in,
                         float* __restrict__ rs_p_out, float* __restrict__ rs_p_in,
                         float* __restrict__ rs_d_out, float* __restrict__ rs_d_in){
  const int idx = blockIdx.x*256 + threadIdx.x;
  const int arr = blockIdx.y;
  int N; size_t hofs; bool pre;
  switch(arr){
    case 0:  N = N_P; hofs = HOFS_A0; pre = false; break;
    case 1:  N = N_D; hofs = HOFS_A1; pre = true;  break;
    case 2:  N = N_D; hofs = HOFS_A2; pre = false; break;
    default: N = N_P; hofs = HOFS_A3; pre = true;  break;
  }
  if (idx >= N) return;
  int* base = hist + hofs + idx;
  int run = 0;
  if (pre){
    #pragma unroll 4
    for (int c = 0; c < NCHK; ++c){
      int v = base[(size_t)c*N]; base[(size_t)c*N] = run; run += v;
    }
  } else {
    #pragma unroll 4
    for (int c = 0; c < NCHK; ++c) run += base[(size_t)c*N];
  }
  float rs = rsqrtf((float)max(run, 1));
  switch(arr){
    case 0:  rs_p_out[idx] = rs; break;
    case 1:  cnt_d_in[idx] = run; rs_d_in[idx] = rs; break;
    case 2:  rs_d_out[idx] = rs; break;
    default: cnt_p_in[idx] = run; rs_p_in[idx] = rs; break;
  }
}

// ---------------- hierarchical exclusive scan -------------------------------
__global__ void k_scan1(const int* __restrict__ cA, int nA,
                        const int* __restrict__ cB, int nB,
                        int* __restrict__ bsums, int nbA){
  __shared__ int red[8];
  int b = blockIdx.x, t = threadIdx.x;
  const int* in; int n, bi, slot;
  if (b < nbA){ in = cA; n = nA; bi = b;       slot = bi; }
  else        { in = cB; n = nB; bi = b - nbA; slot = 256 + bi; }
  int i = bi*512 + t;
  int v = (i < n) ? in[i] : 0;
  #pragma unroll
  for (int o = 32; o; o >>= 1) v += __shfl_down(v, o, 64);
  if ((t & 63) == 0) red[t >> 6] = v;
  __syncthreads();
  if (t == 0){ int s = 0; for (int k = 0; k < 8; ++k) s += red[k]; bsums[slot] = s; }
}

__global__ void k_scan2(int* bsums, int nbA, int nbB){
  __shared__ int sh[256];
  int seg = blockIdx.x, t = threadIdx.x;
  int nb = seg ? nbB : nbA;
  int* p = bsums + seg*256;
  int v = (t < nb) ? p[t] : 0;
  sh[t] = v; __syncthreads();
  for (int ofs = 1; ofs < 256; ofs <<= 1){
    int u = (t >= ofs) ? sh[t-ofs] : 0; __syncthreads();
    sh[t] += u; __syncthreads();
  }
  if (t < nb) p[t] = sh[t] - v;   // exclusive
}

__global__ void k_scan3(const int* __restrict__ cA, int nA,
                        const int* __restrict__ cB, int nB,
                        const int* __restrict__ bsums, int nbA,
                        int* __restrict__ offA, int* __restrict__ offB){
  __shared__ int sh[512];
  int b = blockIdx.x, t = threadIdx.x;
  const int* in; int n, bi; int* out; int base;
  if (b < nbA){ in = cA; n = nA; bi = b;       out = offA; base = bsums[bi]; }
  else        { in = cB; n = nB; bi = b - nbA; out = offB; base = bsums[256+bi]; }
  int i = bi*512 + t;
  int v = (i < n) ? in[i] : 0;
  sh[t] = v; __syncthreads();
  for (int ofs = 1; ofs < 512; ofs <<= 1){
    int u = (t >= ofs) ? sh[t-ofs] : 0; __syncthreads();
    sh[t] += u; __syncthreads();
  }
  if (i < n) out[i] = base + sh[t] - v;
  if (b == 0 && t == 0){ offA[nA] = NE; offB[nB] = NE; }
}

// ---------------- phase 3: scatter (LDS-ranked, zero global atomics) --------
__global__ __launch_bounds__(256) void k_scatter(
    const int* __restrict__ pd_src, const int* __restrict__ pd_dst,
    const int* __restrict__ dp_src, const int* __restrict__ dp_dst,
    const int* __restrict__ off_pd, const int* __restrict__ off_dp,
    const int* __restrict__ hist,
    int* __restrict__ col_pd, int* __restrict__ col_dp){
  __shared__ int base[HPART_P];
  __shared__ int fill[HPART_P];
  const int b = blockIdx.x;
  const int gph = b >> 9, part = (b >> 5) & 15, chunk = b & 31;
  const int* dsts; const int* srcs; const int* off; int* col; int N; size_t hofs;
  if (gph == 0){ dsts = pd_dst; srcs = pd_src; off = off_pd; col = col_pd; N = N_D; hofs = HOFS_A1; }
  else         { dsts = dp_dst; srcs = dp_src; off = off_dp; col = col_dp; N = N_P; hofs = HOFS_A3; }
  const int PART = N / HPARTS;
  const int lo = part * PART;
  const int* hc   = hist + hofs + (size_t)chunk*N + lo;
  const int* offp = off + lo;
  for (int i = threadIdx.x; i < PART; i += 256){ base[i] = offp[i] + hc[i]; fill[i] = 0; }
  __syncthreads();
  const int e0 = chunk*CHKE, e1 = min(e0 + CHKE, NE);
  const uint4* d4 = (const uint4*)(dsts + e0);
  const int n4 = (e1 - e0) >> 2;
  for (int i = threadIdx.x; i < n4; i += 256){
    uint4 d = d4[i];
    int a0 = (int)d.x - lo, a1 = (int)d.y - lo, a2 = (int)d.z - lo, a3 = (int)d.w - lo;
    int e = e0 + 4*i;
    if ((unsigned)a0 < (unsigned)PART){ int r = atomicAdd(&fill[a0], 1); col[base[a0] + r] = srcs[e+0]; }
    if ((unsigned)a1 < (unsigned)PART){ int r = atomicAdd(&fill[a1], 1); col[base[a1] + r] = srcs[e+1]; }
    if ((unsigned)a2 < (unsigned)PART){ int r = atomicAdd(&fill[a2], 1); col[base[a2] + r] = srcs[e+2]; }
    if ((unsigned)a3 < (unsigned)PART){ int r = atomicAdd(&fill[a3], 1); col[base[a3] + r] = srcs[e+3]; }
  }
}

// ---------------- fp32 -> prescaled bf16 feature conversion ----------------
__global__ void k_convert(const float4* __restrict__ hp, const float4* __restrict__ hd,
                          const float* __restrict__ rs_po, const float* __restrict__ rs_do,
                          uint2* __restrict__ P0, uint2* __restrict__ D0){
  int i = blockIdx.x*256 + threadIdx.x;
  const int nP4 = N_P*F/4, nD4 = N_D*F/4;
  if (i < nP4){
    float4 v = hp[i]; float s = rs_po[i >> 5];
    uint2 r;
    r.x = ((uint32_t)f2bf(v.y*s)<<16) | f2bf(v.x*s);
    r.y = ((uint32_t)f2bf(v.w*s)<<16) | f2bf(v.z*s);
    P0[i] = r;
  } else {
    int j = i - nP4;
    if (j < nD4){
      float4 v = hd[j]; float s = rs_do[j >> 5];
      uint2 r;
      r.x = ((uint32_t)f2bf(v.y*s)<<16) | f2bf(v.x*s);
      r.y = ((uint32_t)f2bf(v.w*s)<<16) | f2bf(v.z*s);
      D0[j] = r;
    }
  }
}

// ------- W (fp32 KxN row-major) -> bf16 W^T padded [N][FP]; + zero rows -----
// block m also zeroes the sentinel row (index n_src) of feature buffer m.
__global__ void k_prepw(const float* w0,const float* w1,const float* w2,
                        const float* w3,const float* w4,const float* w5,
                        uint16_t* __restrict__ wt,
                        uint16_t* z0, uint16_t* z1, uint16_t* z2,
                        uint16_t* z3, uint16_t* z4, uint16_t* z5){
  int m = blockIdx.x;
  const float* W; uint16_t* Z;
  switch(m){ case 0:W=w0;Z=z0;break; case 1:W=w1;Z=z1;break; case 2:W=w2;Z=z2;break;
             case 3:W=w3;Z=z3;break; case 4:W=w4;Z=z4;break; default:W=w5;Z=z5; }
  uint16_t* T = wt + m*F*FP;
  for (int idx = threadIdx.x; idx < F*F; idx += 256){
    int k = idx >> 7, j = idx & 127;
    T[j*FP + k] = f2bf(W[idx]);
  }
  if (threadIdx.x < F) Z[threadIdx.x] = 0;   // sentinel zero row
}

// ---------------- fused gconv PAIR ------------------------------------------
// Gather: wave = 4 groups of 16 lanes; group g owns a row, lane l holds
// features [8l,8l+8). col batched 16-wide coalesced + __shfl broadcast;
// invalid edge slots load the zeroed sentinel row (index n_src) -> branch-free
// accumulate. MFMA B-fragments + bias read directly from global (L1-resident).
template<int OUT_MODE>
__global__ __launch_bounds__(256, 7) void k_gconv2(
    const uint16_t* __restrict__ xA, const int* __restrict__ offAp, const int* __restrict__ colA,
    const float* __restrict__ rsA, const uint16_t* __restrict__ WtA, const float* __restrict__ biasA,
    const float* __restrict__ rsnA, void* __restrict__ outA, int ndA, int nsA, int nblkA,
    const uint16_t* __restrict__ xB, const int* __restrict__ offBp, const int* __restrict__ colB,
    const float* __restrict__ rsB, const uint16_t* __restrict__ WtB, const float* __restrict__ biasB,
    const float* __restrict__ rsnB, void* __restrict__ outB, int ndB, int nsB)
{
  __shared__ uint16_t m_lds[64*FP];    // 17408 B
  const int tid  = threadIdx.x;
  const int lane = tid & 63;
  const int wv   = tid >> 6;

  const uint16_t* x; const int* off; const int* col; const float* rs_in;
  const uint16_t* Wt; const float* bias; const float* rs_next; void* outp;
  int n_dst, zrow, bid;
  if ((int)blockIdx.x < nblkA){
    x = xA; off = offAp; col = colA; rs_in = rsA; Wt = WtA; bias = biasA;
    rs_next = rsnA; outp = outA; n_dst = ndA; zrow = nsA; bid = blockIdx.x;
  } else {
    x = xB; off = offBp; col = colB; rs_in = rsB; Wt = WtB; bias = biasB;
    rs_next = rsnB; outp = outB; n_dst = ndB; zrow = nsB; bid = blockIdx.x - nblkA;
  }

  // ---- aggregation ----
  const int row0 = bid*64 + wv*16;
  const int g    = lane >> 4;     // group
  const int l    = lane & 15;     // lane in group; features [8l, 8l+8)
  #pragma unroll
  for (int i = 0; i < 4; ++i){
    int r = row0 + i*4 + g;
    bool rv = r < n_dst;
    int e0 = rv ? off[r]   : 0;
    int e1 = rv ? off[r+1] : 0;
    float a0=0.f,a1=0.f,a2=0.f,a3=0.f,a4=0.f,a5=0.f,a6=0.f,a7=0.f;
    for (int e = e0; e < e1; e += 16){
      int idx = e + l;
      int cv  = col[idx < e1 ? idx : e1-1];   // coalesced 16-wide batch
      int cnt = e1 - e;
      #pragma unroll
      for (int h = 0; h < 2; ++h){
        if (h*8 < cnt){                       // skip empty half-batch
          #pragma unroll
          for (int q = h*8; q < h*8 + 8; ++q){
            int c = __shfl(cv, g*16 + q, 64);
            c = (q < cnt) ? c : zrow;         // sentinel row = zeros
            uint4 u = *(const uint4*)(x + (size_t)c*F + l*8);
            a0 += bf2f((uint16_t)u.x); a1 += bf2f((uint16_t)(u.x>>16));
            a2 += bf2f((uint16_t)u.y); a3 += bf2f((uint16_t)(u.y>>16));
            a4 += bf2f((uint16_t)u.z); a5 += bf2f((uint16_t)(u.z>>16));
            a6 += bf2f((uint16_t)u.w); a7 += bf2f((uint16_t)(u.w>>16));
          }
        }
      }
    }
    float rs = rv ? rs_in[r] : 0.f;
    uint4 pk;
    pk.x = ((uint32_t)f2bf(a1*rs)<<16) | f2bf(a0*rs);
    pk.y = ((uint32_t)f2bf(a3*rs)<<16) | f2bf(a2*rs);
    pk.z = ((uint32_t)f2bf(a5*rs)<<16) | f2bf(a4*rs);
    pk.w = ((uint32_t)f2bf(a7*rs)<<16) | f2bf(a6*rs);
    *(uint4*)&m_lds[(wv*16 + i*4 + g)*FP + l*8] = pk;
  }
  __syncthreads();

  // ---- GEMM: 16 rows x 128 cols per wave; B-fragments from global ----
  f32x4 acc[8];
  #pragma unroll
  for (int t = 0; t < 8; ++t) acc[t] = (f32x4){0.f,0.f,0.f,0.f};
  const int mrow = lane & 15;        // A row / B col within tile
  const int kgrp = lane >> 4;        // k-slice group of 8
  #pragma unroll
  for (int k0 = 0; k0 < F; k0 += 32){
    bf16x8 a = *(const bf16x8*)&m_lds[(wv*16 + mrow)*FP + k0 + kgrp*8];
    #pragma unroll
    for (int t = 0; t < 8; ++t){
      bf16x8 b = *(const bf16x8*)&Wt[(t*16 + mrow)*FP + k0 + kgrp*8];
      acc[t] = __builtin_amdgcn_mfma_f32_16x16x32_bf16(a, b, acc[t], 0, 0, 0);
    }
  }

  // ---- epilogue: + bias, relu, (scale for next layer), store ----
  float bv[8];
  #pragma unroll
  for (int t = 0; t < 8; ++t) bv[t] = bias[t*16 + mrow];
  #pragma unroll
  for (int reg = 0; reg < 4; ++reg){
    int rr = row0 + kgrp*4 + reg;    // D row = (lane>>4)*4 + reg  [m89]
    if (rr < n_dst){
      float rsn = (OUT_MODE == 0) ? rs_next[rr] : 0.f;
      #pragma unroll
      for (int t = 0; t < 8; ++t){
        int n = t*16 + mrow;         // D col = lane&15
        float v = acc[t][reg] + bv[t];
        v = fmaxf(v, 0.f);
        if (OUT_MODE == 0){
          ((uint16_t*)outp)[rr*F + n] = f2bf(v * rsn);
        } else {
          ((float*)outp)[rr*F + n] = v;
        }
      }
    }
  }
}

extern "C" void kernel_launch(void* const* d_in, const int* in_sizes, int n_in,
                              void* d_out, int out_size, void* d_ws, size_t ws_size,
                              hipStream_t stream) {
  const float* h_p   = (const float*)d_in[0];
  const float* h_d   = (const float*)d_in[1];
  const int* pd_src  = (const int*)d_in[2];
  const int* pd_dst  = (const int*)d_in[3];
  const int* dp_src  = (const int*)d_in[4];
  const int* dp_dst  = (const int*)d_in[5];
  const float* W1_pd = (const float*)d_in[6];   const float* b1_pd = (const float*)d_in[7];
  const float* W1_dp = (const float*)d_in[8];   const float* b1_dp = (const float*)d_in[9];
  const float* W2_pd = (const float*)d_in[10];  const float* b2_pd = (const float*)d_in[11];
  const float* W2_dp = (const float*)d_in[12];  const float* b2_dp = (const float*)d_in[13];
  const float* W3_pd = (const float*)d_in[14];  const float* b3_pd = (const float*)d_in[15];
  const float* W3_dp = (const float*)d_in[16];  const float* b3_dp = (const float*)d_in[17];

  char* w = (char*)d_ws;
  size_t o = 0;
  auto take = [&](size_t bytes)->char*{
    char* p = w + o; o += (bytes + 255) & ~(size_t)255; return p;
  };

  int* cnt_d_in  = (int*)take(4*(size_t)N_D);
  int* cnt_p_in  = (int*)take(4*(size_t)N_P);
  int* off_pd   = (int*)take(4*(size_t)(N_D+1));
  int* off_dp   = (int*)take(4*(size_t)(N_P+1));
  int* bsums    = (int*)take(4*512);
  int* col_pd   = (int*)take(4*(size_t)NE);
  int* col_dp   = (int*)take(4*(size_t)NE);
  float* rs_p_out = (float*)take(4*(size_t)N_P);
  float* rs_p_in  = (float*)take(4*(size_t)N_P);
  float* rs_d_out = (float*)take(4*(size_t)N_D);
  float* rs_d_in  = (float*)take(4*(size_t)N_D);
  uint16_t* wt  = (uint16_t*)take(2*(size_t)6*F*FP);
  // feature buffers have n+1 rows; row n is the zeroed sentinel
  uint16_t* P0  = (uint16_t*)take(2*(size_t)(N_P+1)*F);
  uint16_t* P1  = (uint16_t*)take(2*(size_t)(N_P+1)*F);
  uint16_t* P2  = (uint16_t*)take(2*(size_t)(N_P+1)*F);
  uint16_t* D0  = (uint16_t*)take(2*(size_t)(N_D+1)*F);
  uint16_t* D1  = (uint16_t*)take(2*(size_t)(N_D+1)*F);
  uint16_t* D2  = (uint16_t*)take(2*(size_t)(N_D+1)*F);

  // hist (38.4 MB) aliases P1+P2 (51.2 MB): dead until k_prepw/gconv, which
  // run strictly after k_scatter on the same stream.
  int* hist = (int*)P1;

  k_hist<<<4*HPARTS*NCHK, 256, 0, stream>>>(pd_src, pd_dst, dp_src, dp_dst, hist);
  k_sumdeg<<<dim3((N_P+255)/256, 4), 256, 0, stream>>>(
      hist, cnt_d_in, cnt_p_in, rs_p_out, rs_p_in, rs_d_out, rs_d_in);
  const int nbA = (N_D + 511)/512;   // 98
  const int nbB = (N_P + 511)/512;   // 196
  k_scan1<<<nbA+nbB, 512, 0, stream>>>(cnt_d_in, N_D, cnt_p_in, N_P, bsums, nbA);
  k_scan2<<<2, 256, 0, stream>>>(bsums, nbA, nbB);
  k_scan3<<<nbA+nbB, 512, 0, stream>>>(cnt_d_in, N_D, cnt_p_in, N_P, bsums, nbA, off_pd, off_dp);
  k_scatter<<<2*HPARTS*NCHK, 256, 0, stream>>>(pd_src, pd_dst, dp_src, dp_dst,
                                               off_pd, off_dp, hist, col_pd, col_dp);
  k_convert<<<((N_P+N_D)*F/4 + 255)/256, 256, 0, stream>>>(
      (const float4*)h_p, (const float4*)h_d, rs_p_out, rs_d_out, (uint2*)P0, (uint2*)D0);
  k_prepw<<<6, 256, 0, stream>>>(W1_pd, W1_dp, W2_pd, W2_dp, W3_pd, W3_dp, wt,
                                 P0 + (size_t)N_P*F, D0 + (size_t)N_D*F,
                                 P1 + (size_t)N_P*F, D1 + (size_t)N_D*F,
                                 P2 + (size_t)N_P*F, D2 + (size_t)N_D*F);

  const int gd = (N_D + 63)/64, gp = (N_P + 63)/64;
  // layer 1 (both directions fused in one dispatch)
  k_gconv2<0><<<gd+gp, 256, 0, stream>>>(
      P0, off_pd, col_pd, rs_d_in, wt + 0*F*FP, b1_pd, rs_d_out, D1, N_D, N_P, gd,
      D0, off_dp, col_dp, rs_p_in, wt + 1*F*FP, b1_dp, rs_p_out, P1, N_P, N_D);
  // layer 2
  k_gconv2<0><<<gd+gp, 256, 0, stream>>>(
      P1, off_pd, col_pd, rs_d_in, wt + 2*F*FP, b2_pd, rs_d_out, D2, N_D, N_P, gd,
      D1, off_dp, col_dp, rs_p_in, wt + 3*F*FP, b2_dp, rs_p_out, P2, N_P, N_D);
  // layer 3 (fp32 outputs: h_p3 first, then h_d3)
  k_gconv2<1><<<gd+gp, 256, 0, stream>>>(
      P2, off_pd, col_pd, rs_d_in, wt + 4*F*FP, b3_pd, nullptr, (float*)d_out + (size_t)N_P*F, N_D, N_P, gd,
      D2, off_dp, col_dp, rs_p_in, wt + 5*F*FP, b3_dp, nullptr, (float*)d_out, N_P, N_D);
}

// Round 6
// 517.071 us; speedup vs baseline: 2.5671x; 1.0318x over previous
//
#include <hip/hip_runtime.h>
#include <stdint.h>

#define N_P 100000
#define N_D 50000
#define NE  600000
#define F   128
#define FP  136   // padded LDS/global row stride (272B = 17*16B: 16B-aligned, 2-way-free banks)

// counting-sort build params
#define NCHK   32
#define CHKE   18752                 // edges per chunk (mult of 4); last chunk = 18688
#define HPARTS 8
#define HPART_P (N_P/HPARTS)         // 12500 -> 50 KB LDS
#define HPART_D (N_D/HPARTS)         // 6250
// hist layout (ints): A0 pd_src[32][N_P] | A1 pd_dst[32][N_D] | A2 dp_src[32][N_D] | A3 dp_dst[32][N_P]
#define HOFS_A0 ((size_t)0)
#define HOFS_A1 ((size_t)32*N_P)
#define HOFS_A2 ((size_t)32*N_P + (size_t)32*N_D)
#define HOFS_A3 ((size_t)32*N_P + (size_t)64*N_D)

typedef __attribute__((ext_vector_type(8))) __bf16 bf16x8;
typedef __attribute__((ext_vector_type(4))) float  f32x4;

static __device__ __forceinline__ float bf2f(uint16_t u){
  union{float f;uint32_t i;} v; v.i = ((uint32_t)u)<<16; return v.f;
}
static __device__ __forceinline__ uint16_t f2bf(float f){
  union{float f;uint32_t i;} v; v.f = f;
  uint32_t i = v.i;
  uint32_t r = i + 0x7fffu + ((i>>16)&1u);   // round-to-nearest-even
  return (uint16_t)(r>>16);
}

// ---------------- phase 1: per-(array, part, chunk) LDS histogram -----------
// grid = 4*HPARTS*NCHK = 1024. 8x stream redundancy (was 16x).
__global__ __launch_bounds__(256) void k_hist(
    const int* __restrict__ pd_src, const int* __restrict__ pd_dst,
    const int* __restrict__ dp_src, const int* __restrict__ dp_dst,
    int* __restrict__ hist){
  __shared__ int cnt[HPART_P];
  const int b = blockIdx.x;
  const int arr = b >> 8, part = (b >> 5) & 7, chunk = b & 31;
  const int* src; int N; size_t hofs;
  switch(arr){
    case 0:  src = pd_src; N = N_P; hofs = HOFS_A0; break;
    case 1:  src = pd_dst; N = N_D; hofs = HOFS_A1; break;
    case 2:  src = dp_src; N = N_D; hofs = HOFS_A2; break;
    default: src = dp_dst; N = N_P; hofs = HOFS_A3; break;
  }
  const int PART = N / HPARTS;
  const int lo = part * PART;
  for (int i = threadIdx.x; i < PART; i += 256) cnt[i] = 0;
  __syncthreads();
  const int e0 = chunk*CHKE, e1 = min(e0 + CHKE, NE);
  const uint4* s4 = (const uint4*)(src + e0);
  const int n4 = (e1 - e0) >> 2;
  for (int i = threadIdx.x; i < n4; i += 256){
    uint4 v = s4[i];
    int a0 = (int)v.x - lo, a1 = (int)v.y - lo, a2 = (int)v.z - lo, a3 = (int)v.w - lo;
    if ((unsigned)a0 < (unsigned)PART) atomicAdd(&cnt[a0], 1);
    if ((unsigned)a1 < (unsigned)PART) atomicAdd(&cnt[a1], 1);
    if ((unsigned)a2 < (unsigned)PART) atomicAdd(&cnt[a2], 1);
    if ((unsigned)a3 < (unsigned)PART) atomicAdd(&cnt[a3], 1);
  }
  __syncthreads();
  int* out = hist + hofs + (size_t)chunk*N + lo;
  for (int i = threadIdx.x; i < PART; i += 256) out[i] = cnt[i];
}

// ---------------- phase 2: chunk-prefix (dst arrays) + degrees + rsqrt ------
__global__ void k_sumdeg(int* __restrict__ hist,
                         int* __restrict__ cnt_d_in, int* __restrict__ cnt_p_in,
                         float* __restrict__ rs_p_out, float* __restrict__ rs_p_in,
                         float* __restrict__ rs_d_out, float* __restrict__ rs_d_in){
  const int idx = blockIdx.x*256 + threadIdx.x;
  const int arr = blockIdx.y;
  int N; size_t hofs; bool pre;
  switch(arr){
    case 0:  N = N_P; hofs = HOFS_A0; pre = false; break;
    case 1:  N = N_D; hofs = HOFS_A1; pre = true;  break;
    case 2:  N = N_D; hofs = HOFS_A2; pre = false; break;
    default: N = N_P; hofs = HOFS_A3; pre = true;  break;
  }
  if (idx >= N) return;
  int* base = hist + hofs + idx;
  int run = 0;
  if (pre){
    #pragma unroll 4
    for (int c = 0; c < NCHK; ++c){
      int v = base[(size_t)c*N]; base[(size_t)c*N] = run; run += v;
    }
  } else {
    #pragma unroll 4
    for (int c = 0; c < NCHK; ++c) run += base[(size_t)c*N];
  }
  float rs = rsqrtf((float)max(run, 1));
  switch(arr){
    case 0:  rs_p_out[idx] = rs; break;
    case 1:  cnt_d_in[idx] = run; rs_d_in[idx] = rs; break;
    case 2:  rs_d_out[idx] = rs; break;
    default: cnt_p_in[idx] = run; rs_p_in[idx] = rs; break;
  }
}

// ---------------- hierarchical exclusive scan -------------------------------
__global__ void k_scan1(const int* __restrict__ cA, int nA,
                        const int* __restrict__ cB, int nB,
                        int* __restrict__ bsums, int nbA){
  __shared__ int red[8];
  int b = blockIdx.x, t = threadIdx.x;
  const int* in; int n, bi, slot;
  if (b < nbA){ in = cA; n = nA; bi = b;       slot = bi; }
  else        { in = cB; n = nB; bi = b - nbA; slot = 256 + bi; }
  int i = bi*512 + t;
  int v = (i < n) ? in[i] : 0;
  #pragma unroll
  for (int o = 32; o; o >>= 1) v += __shfl_down(v, o, 64);
  if ((t & 63) == 0) red[t >> 6] = v;
  __syncthreads();
  if (t == 0){ int s = 0; for (int k = 0; k < 8; ++k) s += red[k]; bsums[slot] = s; }
}

__global__ void k_scan2(int* bsums, int nbA, int nbB){
  __shared__ int sh[256];
  int seg = blockIdx.x, t = threadIdx.x;
  int nb = seg ? nbB : nbA;
  int* p = bsums + seg*256;
  int v = (t < nb) ? p[t] : 0;
  sh[t] = v; __syncthreads();
  for (int ofs = 1; ofs < 256; ofs <<= 1){
    int u = (t >= ofs) ? sh[t-ofs] : 0; __syncthreads();
    sh[t] += u; __syncthreads();
  }
  if (t < nb) p[t] = sh[t] - v;   // exclusive
}

__global__ void k_scan3(const int* __restrict__ cA, int nA,
                        const int* __restrict__ cB, int nB,
                        const int* __restrict__ bsums, int nbA,
                        int* __restrict__ offA, int* __restrict__ offB){
  __shared__ int sh[512];
  int b = blockIdx.x, t = threadIdx.x;
  const int* in; int n, bi; int* out; int base;
  if (b < nbA){ in = cA; n = nA; bi = b;       out = offA; base = bsums[bi]; }
  else        { in = cB; n = nB; bi = b - nbA; out = offB; base = bsums[256+bi]; }
  int i = bi*512 + t;
  int v = (i < n) ? in[i] : 0;
  sh[t] = v; __syncthreads();
  for (int ofs = 1; ofs < 512; ofs <<= 1){
    int u = (t >= ofs) ? sh[t-ofs] : 0; __syncthreads();
    sh[t] += u; __syncthreads();
  }
  if (i < n) out[i] = base + sh[t] - v;
  if (b == 0 && t == 0){ offA[nA] = NE; offB[nB] = NE; }
}

// ---------------- phase 3: scatter ------------------------------------------
// grid = 2*HPARTS*NCHK = 512. base[] doubles as the rank counter (LDS
// atomicAdd returns the write position directly). 8x redundancy (was 16x).
__global__ __launch_bounds__(256) void k_scatter(
    const int* __restrict__ pd_src, const int* __restrict__ pd_dst,
    const int* __restrict__ dp_src, const int* __restrict__ dp_dst,
    const int* __restrict__ off_pd, const int* __restrict__ off_dp,
    const int* __restrict__ hist,
    int* __restrict__ col_pd, int* __restrict__ col_dp){
  __shared__ int base[HPART_P];
  const int b = blockIdx.x;
  const int gph = b >> 8, part = (b >> 5) & 7, chunk = b & 31;
  const int* dsts; const int* srcs; const int* off; int* col; int N; size_t hofs;
  if (gph == 0){ dsts = pd_dst; srcs = pd_src; off = off_pd; col = col_pd; N = N_D; hofs = HOFS_A1; }
  else         { dsts = dp_dst; srcs = dp_src; off = off_dp; col = col_dp; N = N_P; hofs = HOFS_A3; }
  const int PART = N / HPARTS;
  const int lo = part * PART;
  const int* hc   = hist + hofs + (size_t)chunk*N + lo;
  const int* offp = off + lo;
  for (int i = threadIdx.x; i < PART; i += 256) base[i] = offp[i] + hc[i];
  __syncthreads();
  const int e0 = chunk*CHKE, e1 = min(e0 + CHKE, NE);
  const uint4* d4 = (const uint4*)(dsts + e0);
  const int n4 = (e1 - e0) >> 2;
  for (int i = threadIdx.x; i < n4; i += 256){
    uint4 d = d4[i];
    int a0 = (int)d.x - lo, a1 = (int)d.y - lo, a2 = (int)d.z - lo, a3 = (int)d.w - lo;
    int e = e0 + 4*i;
    if ((unsigned)a0 < (unsigned)PART){ int p = atomicAdd(&base[a0], 1); col[p] = srcs[e+0]; }
    if ((unsigned)a1 < (unsigned)PART){ int p = atomicAdd(&base[a1], 1); col[p] = srcs[e+1]; }
    if ((unsigned)a2 < (unsigned)PART){ int p = atomicAdd(&base[a2], 1); col[p] = srcs[e+2]; }
    if ((unsigned)a3 < (unsigned)PART){ int p = atomicAdd(&base[a3], 1); col[p] = srcs[e+3]; }
  }
}

// ------ merged: W prep (blocks 0..5) + fp32->prescaled bf16 convert ---------
__global__ void k_convert(const float4* __restrict__ hp, const float4* __restrict__ hd,
                          const float* __restrict__ rs_po, const float* __restrict__ rs_do,
                          uint2* __restrict__ P0, uint2* __restrict__ D0,
                          const float* w0,const float* w1,const float* w2,
                          const float* w3,const float* w4,const float* w5,
                          uint16_t* __restrict__ wt,
                          uint16_t* z0, uint16_t* z1, uint16_t* z2,
                          uint16_t* z3, uint16_t* z4, uint16_t* z5){
  if (blockIdx.x < 6){
    int m = blockIdx.x;
    const float* W; uint16_t* Z;
    switch(m){ case 0:W=w0;Z=z0;break; case 1:W=w1;Z=z1;break; case 2:W=w2;Z=z2;break;
               case 3:W=w3;Z=z3;break; case 4:W=w4;Z=z4;break; default:W=w5;Z=z5; }
    uint16_t* T = wt + m*F*FP;
    for (int idx = threadIdx.x; idx < F*F; idx += 256){
      int k = idx >> 7, j = idx & 127;
      T[j*FP + k] = f2bf(W[idx]);
    }
    if (threadIdx.x < F) Z[threadIdx.x] = 0;   // sentinel zero row
    return;
  }
  int i = (blockIdx.x - 6)*256 + threadIdx.x;
  const int nP4 = N_P*F/4, nD4 = N_D*F/4;
  if (i < nP4){
    float4 v = hp[i]; float s = rs_po[i >> 5];
    uint2 r;
    r.x = ((uint32_t)f2bf(v.y*s)<<16) | f2bf(v.x*s);
    r.y = ((uint32_t)f2bf(v.w*s)<<16) | f2bf(v.z*s);
    P0[i] = r;
  } else {
    int j = i - nP4;
    if (j < nD4){
      float4 v = hd[j]; float s = rs_do[j >> 5];
      uint2 r;
      r.x = ((uint32_t)f2bf(v.y*s)<<16) | f2bf(v.x*s);
      r.y = ((uint32_t)f2bf(v.w*s)<<16) | f2bf(v.z*s);
      D0[j] = r;
    }
  }
}

// ---------------- fused gconv PAIR ------------------------------------------
// Gather: wave = 4 groups of 16 lanes; group g owns a row, lane l holds
// features [8l,8l+8). First col batch of all 4 rows hoisted (4 loads in
// flight); next batch prefetched unconditionally inside the loop.
// GEMM operand-swap: A := W^T tile, B := aggregated rows. D: col(lane&15) =
// dst-row, row(quad*4+reg) = out-col -> each lane owns 1 row, 4 consecutive
// cols per tile -> vectorized 8B/16B epilogue stores. m_lds is wave-private
// and Wt comes from global, so no __syncthreads at all.
template<int OUT_MODE>
__global__ __launch_bounds__(256, 7) void k_gconv2(
    const uint16_t* __restrict__ xA, const int* __restrict__ offAp, const int* __restrict__ colA,
    const float* __restrict__ rsA, const uint16_t* __restrict__ WtA, const float* __restrict__ biasA,
    const float* __restrict__ rsnA, void* __restrict__ outA, int ndA, int nsA, int nblkA,
    const uint16_t* __restrict__ xB, const int* __restrict__ offBp, const int* __restrict__ colB,
    const float* __restrict__ rsB, const uint16_t* __restrict__ WtB, const float* __restrict__ biasB,
    const float* __restrict__ rsnB, void* __restrict__ outB, int ndB, int nsB)
{
  __shared__ uint16_t m_lds[64*FP];    // 17408 B
  const int tid  = threadIdx.x;
  const int lane = tid & 63;
  const int wv   = tid >> 6;

  const uint16_t* x; const int* off; const int* col; const float* rs_in;
  const uint16_t* Wt; const float* bias; const float* rs_next; void* outp;
  int n_dst, zrow, bid;
  if ((int)blockIdx.x < nblkA){
    x = xA; off = offAp; col = colA; rs_in = rsA; Wt = WtA; bias = biasA;
    rs_next = rsnA; outp = outA; n_dst = ndA; zrow = nsA; bid = blockIdx.x;
  } else {
    x = xB; off = offBp; col = colB; rs_in = rsB; Wt = WtB; bias = biasB;
    rs_next = rsnB; outp = outB; n_dst = ndB; zrow = nsB; bid = blockIdx.x - nblkA;
  }

  // ---- aggregation ----
  const int row0 = bid*64 + wv*16;
  const int g    = lane >> 4;     // group
  const int l    = lane & 15;     // lane in group; features [8l, 8l+8)

  int e0a[4], e1a[4], cva[4];
  #pragma unroll
  for (int i = 0; i < 4; ++i){
    int r = row0 + i*4 + g;
    bool rv = r < n_dst;
    e0a[i] = rv ? off[r]   : 0;
    e1a[i] = rv ? off[r+1] : 0;
  }
  #pragma unroll
  for (int i = 0; i < 4; ++i){
    int last = (e1a[i] > 0) ? e1a[i]-1 : 0;
    int idx  = e0a[i] + l;
    cva[i] = col[idx < e1a[i] ? idx : last];   // hoisted first batch (4 loads in flight)
  }

  #pragma unroll
  for (int i = 0; i < 4; ++i){
    int e0 = e0a[i], e1 = e1a[i];
    int cv = cva[i];
    float a0=0.f,a1=0.f,a2=0.f,a3=0.f,a4=0.f,a5=0.f,a6=0.f,a7=0.f;
    for (int e = e0; e < e1; e += 16){
      // prefetch next batch (clamped; harmless L1-hit re-read on last batch)
      int nidx = e + 16 + l;
      int ncv  = col[nidx < e1 ? nidx : e1-1];
      int cnt  = e1 - e;
      #pragma unroll
      for (int h = 0; h < 2; ++h){
        if (h*8 < cnt){                       // skip empty half-batch
          #pragma unroll
          for (int q = h*8; q < h*8 + 8; ++q){
            int c = __shfl(cv, g*16 + q, 64);
            c = (q < cnt) ? c : zrow;         // sentinel row = zeros
            uint4 u = *(const uint4*)(x + (size_t)c*F + l*8);
            a0 += bf2f((uint16_t)u.x); a1 += bf2f((uint16_t)(u.x>>16));
            a2 += bf2f((uint16_t)u.y); a3 += bf2f((uint16_t)(u.y>>16));
            a4 += bf2f((uint16_t)u.z); a5 += bf2f((uint16_t)(u.z>>16));
            a6 += bf2f((uint16_t)u.w); a7 += bf2f((uint16_t)(u.w>>16));
          }
        }
      }
      cv = ncv;
    }
    int r = row0 + i*4 + g;
    float rs = (r < n_dst) ? rs_in[r] : 0.f;
    uint4 pk;
    pk.x = ((uint32_t)f2bf(a1*rs)<<16) | f2bf(a0*rs);
    pk.y = ((uint32_t)f2bf(a3*rs)<<16) | f2bf(a2*rs);
    pk.z = ((uint32_t)f2bf(a5*rs)<<16) | f2bf(a4*rs);
    pk.w = ((uint32_t)f2bf(a7*rs)<<16) | f2bf(a6*rs);
    *(uint4*)&m_lds[(wv*16 + i*4 + g)*FP + l*8] = pk;
  }
  // no barrier: m_lds rows are wave-private, same-wave ds ordering is implicit

  // ---- GEMM (operand-swapped): A = W^T tile, B = aggregated rows ----
  f32x4 acc[8];
  #pragma unroll
  for (int t = 0; t < 8; ++t) acc[t] = (f32x4){0.f,0.f,0.f,0.f};
  const int mrow = lane & 15;
  const int kgrp = lane >> 4;
  #pragma unroll
  for (int k0 = 0; k0 < F; k0 += 32){
    bf16x8 bfrag = *(const bf16x8*)&m_lds[(wv*16 + mrow)*FP + k0 + kgrp*8];
    #pragma unroll
    for (int t = 0; t < 8; ++t){
      bf16x8 afrag = *(const bf16x8*)&Wt[(t*16 + mrow)*FP + k0 + kgrp*8];
      acc[t] = __builtin_amdgcn_mfma_f32_16x16x32_bf16(afrag, bfrag, acc[t], 0, 0, 0);
    }
  }

  // ---- epilogue: lane owns dst-row rr, cols t*16 + quad*4 + (0..3) ----
  const int q4 = kgrp * 4;
  const int rr = row0 + mrow;
  if (rr < n_dst){
    float rsn = (OUT_MODE == 0) ? rs_next[rr] : 1.f;
    #pragma unroll
    for (int t = 0; t < 8; ++t){
      float4 b4 = *(const float4*)&bias[t*16 + q4];
      float v0 = fmaxf(acc[t][0] + b4.x, 0.f);
      float v1 = fmaxf(acc[t][1] + b4.y, 0.f);
      float v2 = fmaxf(acc[t][2] + b4.z, 0.f);
      float v3 = fmaxf(acc[t][3] + b4.w, 0.f);
      if (OUT_MODE == 0){
        uint2 pk;
        pk.x = ((uint32_t)f2bf(v1*rsn)<<16) | f2bf(v0*rsn);
        pk.y = ((uint32_t)f2bf(v3*rsn)<<16) | f2bf(v2*rsn);
        *(uint2*)((uint16_t*)outp + (size_t)rr*F + t*16 + q4) = pk;
      } else {
        float4 o; o.x = v0; o.y = v1; o.z = v2; o.w = v3;
        *(float4*)((float*)outp + (size_t)rr*F + t*16 + q4) = o;
      }
    }
  }
}

extern "C" void kernel_launch(void* const* d_in, const int* in_sizes, int n_in,
                              void* d_out, int out_size, void* d_ws, size_t ws_size,
                              hipStream_t stream) {
  const float* h_p   = (const float*)d_in[0];
  const float* h_d   = (const float*)d_in[1];
  const int* pd_src  = (const int*)d_in[2];
  const int* pd_dst  = (const int*)d_in[3];
  const int* dp_src  = (const int*)d_in[4];
  const int* dp_dst  = (const int*)d_in[5];
  const float* W1_pd = (const float*)d_in[6];   const float* b1_pd = (const float*)d_in[7];
  const float* W1_dp = (const float*)d_in[8];   const float* b1_dp = (const float*)d_in[9];
  const float* W2_pd = (const float*)d_in[10];  const float* b2_pd = (const float*)d_in[11];
  const float* W2_dp = (const float*)d_in[12];  const float* b2_dp = (const float*)d_in[13];
  const float* W3_pd = (const float*)d_in[14];  const float* b3_pd = (const float*)d_in[15];
  const float* W3_dp = (const float*)d_in[16];  const float* b3_dp = (const float*)d_in[17];

  char* w = (char*)d_ws;
  size_t o = 0;
  auto take = [&](size_t bytes)->char*{
    char* p = w + o; o += (bytes + 255) & ~(size_t)255; return p;
  };

  int* cnt_d_in  = (int*)take(4*(size_t)N_D);
  int* cnt_p_in  = (int*)take(4*(size_t)N_P);
  int* off_pd   = (int*)take(4*(size_t)(N_D+1));
  int* off_dp   = (int*)take(4*(size_t)(N_P+1));
  int* bsums    = (int*)take(4*512);
  int* col_pd   = (int*)take(4*(size_t)NE);
  int* col_dp   = (int*)take(4*(size_t)NE);
  float* rs_p_out = (float*)take(4*(size_t)N_P);
  float* rs_p_in  = (float*)take(4*(size_t)N_P);
  float* rs_d_out = (float*)take(4*(size_t)N_D);
  float* rs_d_in  = (float*)take(4*(size_t)N_D);
  uint16_t* wt  = (uint16_t*)take(2*(size_t)6*F*FP);
  // feature buffers have n+1 rows; row n is the zeroed sentinel
  uint16_t* P0  = (uint16_t*)take(2*(size_t)(N_P+1)*F);
  uint16_t* P1  = (uint16_t*)take(2*(size_t)(N_P+1)*F);
  uint16_t* P2  = (uint16_t*)take(2*(size_t)(N_P+1)*F);
  uint16_t* D0  = (uint16_t*)take(2*(size_t)(N_D+1)*F);
  uint16_t* D1  = (uint16_t*)take(2*(size_t)(N_D+1)*F);
  uint16_t* D2  = (uint16_t*)take(2*(size_t)(N_D+1)*F);

  // hist (38.4 MB) aliases P1+P2 (51.2 MB): dead until k_convert/gconv, which
  // run strictly after k_scatter on the same stream.
  int* hist = (int*)P1;

  k_hist<<<4*HPARTS*NCHK, 256, 0, stream>>>(pd_src, pd_dst, dp_src, dp_dst, hist);
  k_sumdeg<<<dim3((N_P+255)/256, 4), 256, 0, stream>>>(
      hist, cnt_d_in, cnt_p_in, rs_p_out, rs_p_in, rs_d_out, rs_d_in);
  const int nbA = (N_D + 511)/512;   // 98
  const int nbB = (N_P + 511)/512;   // 196
  k_scan1<<<nbA+nbB, 512, 0, stream>>>(cnt_d_in, N_D, cnt_p_in, N_P, bsums, nbA);
  k_scan2<<<2, 256, 0, stream>>>(bsums, nbA, nbB);
  k_scan3<<<nbA+nbB, 512, 0, stream>>>(cnt_d_in, N_D, cnt_p_in, N_P, bsums, nbA, off_pd, off_dp);
  k_scatter<<<2*HPARTS*NCHK, 256, 0, stream>>>(pd_src, pd_dst, dp_src, dp_dst,
                                               off_pd, off_dp, hist, col_pd, col_dp);
  k_convert<<<((N_P+N_D)*F/4 + 255)/256 + 6, 256, 0, stream>>>(
      (const float4*)h_p, (const float4*)h_d, rs_p_out, rs_d_out, (uint2*)P0, (uint2*)D0,
      W1_pd, W1_dp, W2_pd, W2_dp, W3_pd, W3_dp, wt,
      P0 + (size_t)N_P*F, D0 + (size_t)N_D*F,
      P1 + (size_t)N_P*F, D1 + (size_t)N_D*F,
      P2 + (size_t)N_P*F, D2 + (size_t)N_D*F);

  const int gd = (N_D + 63)/64, gp = (N_P + 63)/64;
  // layer 1 (both directions fused in one dispatch)
  k_gconv2<0><<<gd+gp, 256, 0, stream>>>(
      P0, off_pd, col_pd, rs_d_in, wt + 0*F*FP, b1_pd, rs_d_out, D1, N_D, N_P, gd,
      D0, off_dp, col_dp, rs_p_in, wt + 1*F*FP, b1_dp, rs_p_out, P1, N_P, N_D);
  // layer 2
  k_gconv2<0><<<gd+gp, 256, 0, stream>>>(
      P1, off_pd, col_pd, rs_d_in, wt + 2*F*FP, b2_pd, rs_d_out, D2, N_D, N_P, gd,
      D1, off_dp, col_dp, rs_p_in, wt + 3*F*FP, b2_dp, rs_p_out, P2, N_P, N_D);
  // layer 3 (fp32 outputs: h_p3 first, then h_d3)
  k_gconv2<1><<<gd+gp, 256, 0, stream>>>(
      P2, off_pd, col_pd, rs_d_in, wt + 4*F*FP, b3_pd, nullptr, (float*)d_out + (size_t)N_P*F, N_D, N_P, gd,
      D2, off_dp, col_dp, rs_p_in, wt + 5*F*FP, b3_dp, nullptr, (float*)d_out, N_P, N_D);
}